// Round 15
// baseline (201.538 us; speedup 1.0000x reference)
//
#include <hip/hip_runtime.h>

#define NUSERS 250000
#define NITEMS 250000
#define NNODES 500000
#define NEDGES 1200000
#define NGROUPS (NNODES/16)  // 31250
#define NCH8   (NNODES/8)    // 62500

#define NB     245           // buckets: dst>>11, 2048 nodes each (last: 288)
#define BCAP   6144          // per-bucket capacity (mean 4898, +17 sigma)
#define SEGE   8192          // edges per phase-A block
#define NBLKA  147           // ceil(NEDGES/SEGE)

typedef _Float16 half_t;
typedef _Float16 half8 __attribute__((ext_vector_type(8)));
typedef _Float16 half4 __attribute__((ext_vector_type(4)));
typedef float    f32x4 __attribute__((ext_vector_type(4)));

// ---------------- CSR build: two-level LDS counting sort ----------------

__global__ void k_zero_gc(int* __restrict__ gc) {
    int t = threadIdx.x;
    if (t < NB) gc[t] = 0;
}

// Phase A: bin edges into 245 coarse buckets with LDS staging; contiguous flush.
__global__ __launch_bounds__(256) void k_bucketA(
    const int* __restrict__ src, const int* __restrict__ dst,
    int* __restrict__ gcursor, unsigned int* __restrict__ gbuf)
{
    __shared__ int ecnt[256];
    __shared__ int ebase[256];
    __shared__ int ecur[256];
    __shared__ int gres[256];
    __shared__ unsigned int stage[SEGE];
    __shared__ unsigned char stb[SEGE];

    const int t = threadIdx.x;
    const int e0 = blockIdx.x * SEGE;
    const int ecount = min(SEGE, NEDGES - e0);

    ecnt[t] = 0;
    __syncthreads();
    for (int k = t; k < ecount; k += 256)
        atomicAdd(&ecnt[dst[e0 + k] >> 11], 1);
    __syncthreads();

    const int v = ecnt[t];
    ebase[t] = v; __syncthreads();
    for (int d = 1; d < 256; d <<= 1) {
        int x = (t >= d) ? ebase[t - d] : 0;
        __syncthreads();
        ebase[t] += x;
        __syncthreads();
    }
    const int excl = ebase[t] - v;
    __syncthreads();
    ebase[t] = excl;
    ecur[t]  = excl;
    if (t < NB && v > 0) gres[t] = atomicAdd(&gcursor[t], v);
    __syncthreads();

    for (int k = t; k < ecount; k += 256) {
        const int s  = src[e0 + k];
        const int d2 = dst[e0 + k];
        const int b  = d2 >> 11;
        const int p  = atomicAdd(&ecur[b], 1);
        stage[p] = ((unsigned int)s << 11) | (unsigned int)(d2 & 2047);
        stb[p]   = (unsigned char)b;
    }
    __syncthreads();

    for (int s = t; s < ecount; s += 256) {
        const int b = stb[s];
        gbuf[(size_t)b * BCAP + gres[b] + (s - ebase[b])] = stage[s];
    }
}

// exclusive scan of the 245 bucket counts -> csr base per bucket
__global__ __launch_bounds__(256) void k_scan_buckets(const int* __restrict__ gcursor,
                                                      int* __restrict__ bbase)
{
    __shared__ int sm[256];
    const int t = threadIdx.x;
    const int v = (t < NB) ? gcursor[t] : 0;
    sm[t] = v; __syncthreads();
    for (int d = 1; d < 256; d <<= 1) {
        int x = (t >= d) ? sm[t - d] : 0;
        __syncthreads();
        sm[t] += x;
        __syncthreads();
    }
    if (t < NB) bbase[t] = sm[t] - v;
}

// Phase B: per bucket -> dinv, offsets, csr (LDS histogram/scan/place, coalesced out)
__global__ __launch_bounds__(256) void k_bucketB(
    const int* __restrict__ gcursor, const int* __restrict__ bbase,
    const unsigned int* __restrict__ gbuf,
    float* __restrict__ dinv, int* __restrict__ offsets, int* __restrict__ csr)
{
    __shared__ int hist[2048];
    __shared__ int cur[2048];
    __shared__ int psum[256];
    __shared__ int lcsr[BCAP];      // 8+8+1+24 = 41 KB LDS

    const int t = threadIdx.x;
    const int b = blockIdx.x;
    const int cnt = gcursor[b];
    const int nbase = b << 11;
    const int nb = min(2048, NNODES - nbase);
    const unsigned int* gb0 = gbuf + (size_t)b * BCAP;
    const int cbase = bbase[b];

    for (int i = t; i < 2048; i += 256) hist[i] = 0;
    __syncthreads();
    for (int s = t; s < cnt; s += 256)
        atomicAdd(&hist[gb0[s] & 2047], 1);
    __syncthreads();

    // dinv straight from histogram (self-loop adds 1)
    for (int i = t; i < nb; i += 256)
        dinv[nbase + i] = 1.0f / sqrtf((float)(hist[i] + 1));

    // exclusive scan of hist -> cur + global offsets
    int loc[8]; int ssum = 0;
#pragma unroll
    for (int k = 0; k < 8; ++k) { loc[k] = hist[t * 8 + k]; ssum += loc[k]; }
    psum[t] = ssum; __syncthreads();
    for (int d = 1; d < 256; d <<= 1) {
        int x = (t >= d) ? psum[t - d] : 0;
        __syncthreads();
        psum[t] += x;
        __syncthreads();
    }
    int run = psum[t] - ssum;
#pragma unroll
    for (int k = 0; k < 8; ++k) {
        const int i = t * 8 + k;
        if (i < nb) offsets[nbase + i] = cbase + run;
        cur[i] = run;
        run += loc[k];
    }
    __syncthreads();
    if (b == NB - 1 && t == 0) offsets[NNODES] = cbase + cnt;

    // place into LDS csr slice, then coalesced flush
    for (int s = t; s < cnt; s += 256) {
        const unsigned int pk = gb0[s];
        const int p = atomicAdd(&cur[pk & 2047], 1);
        lcsr[p] = (int)(pk >> 11);
    }
    __syncthreads();
    for (int s = t; s < cnt; s += 256)
        csr[cbase + s] = lcsr[s];
}

// ---------------- MFMA helpers ----------------
// A: lane holds row (lane&15), k = 32q + 8*(lane>>4) + j
// B: lane holds col-slot (lane&15), same k formula; out-feature = 4*(lane&15)+c
// C/D: node = n0 + (lane>>4)*4 + r, feat = 4*(lane&15)+c

__device__ __forceinline__ void build_bfrags(const float* __restrict__ W,
                                             int lg, int cl, half8 bf[2][4]) {
#pragma unroll
    for (int q = 0; q < 2; ++q)
#pragma unroll
        for (int c = 0; c < 4; ++c) {
            half8 v;
#pragma unroll
            for (int j = 0; j < 8; ++j)
                v[j] = (half_t)W[(32 * q + 8 * lg + j) * 64 + 4 * cl + c];
            bf[q][c] = v;
        }
}

// ---------------- k_mm1: g1 = (gather(emb) @ W1) * dinv  [fp16 out] ----------------
// 3-stage pipeline: row POINTERS (from uid/iid) are resolved one iteration
// before the row loads are issued, which are one iteration before use.
// Breaks the id-load -> row-load serial chain.

__global__ __launch_bounds__(256) void k_mm1(
    const float* __restrict__ user_table, const float* __restrict__ item_table,
    const int* __restrict__ uid, const int* __restrict__ iid,
    const float* __restrict__ W1, const float* __restrict__ dinv,
    half_t* __restrict__ g)
{
    const int lane = threadIdx.x & 63;
    const int lg = lane >> 4, cl = lane & 15;
    const int wid = blockIdx.x * (blockDim.x >> 6) + (threadIdx.x >> 6);
    const int nw  = gridDim.x * (blockDim.x >> 6);

    half8 bf[2][4];
    build_bfrags(W1, lg, cl, bf);
    const f32x4 zacc = {0.f, 0.f, 0.f, 0.f};

    if (wid >= NGROUPS) return;

    // resolve row pointer for tile tt (clamped to a safe always-valid tile)
    #define ROWPTR(tt) ({                                                     \
        const int ttc_ = ((tt) < NGROUPS) ? (tt) : wid;                       \
        const int na_ = ttc_ * 16 + cl;                                       \
        (na_ < NUSERS) ? user_table + (size_t)uid[na_] * 64                   \
                       : item_table + (size_t)iid[na_ - NUSERS] * 64; })

    int t = wid;
    const float* pcur  = ROWPTR(t);            // id chain: first iter only
    f32x4 u0 = *(const f32x4*)(pcur + 8 * lg);
    f32x4 u1 = *(const f32x4*)(pcur + 8 * lg + 4);
    f32x4 u2 = *(const f32x4*)(pcur + 8 * lg + 32);
    f32x4 u3 = *(const f32x4*)(pcur + 8 * lg + 36);
    const float* pnext = ROWPTR(t + nw);       // id for t+nw already in flight

    while (t < NGROUPS) {
        const int tn = t + nw;
        // rows for t+nw (pointer resolved last iteration)
        f32x4 v0 = *(const f32x4*)(pnext + 8 * lg);
        f32x4 v1 = *(const f32x4*)(pnext + 8 * lg + 4);
        f32x4 v2 = *(const f32x4*)(pnext + 8 * lg + 32);
        f32x4 v3 = *(const f32x4*)(pnext + 8 * lg + 36);
        // id for t+2nw
        const float* pnn = ROWPTR(tn + nw);

        const int n0 = t * 16;
        half8 a0, a1;
#pragma unroll
        for (int j = 0; j < 4; ++j) {
            a0[j] = (half_t)u0[j]; a0[4 + j] = (half_t)u1[j];
            a1[j] = (half_t)u2[j]; a1[4 + j] = (half_t)u3[j];
        }
        f32x4 acc[4];
#pragma unroll
        for (int c = 0; c < 4; ++c) {
            acc[c] = __builtin_amdgcn_mfma_f32_16x16x32_f16(a0, bf[0][c], zacc, 0, 0, 0);
            acc[c] = __builtin_amdgcn_mfma_f32_16x16x32_f16(a1, bf[1][c], acc[c], 0, 0, 0);
        }
#pragma unroll
        for (int r = 0; r < 4; ++r) {
            const int nd = n0 + lg * 4 + r;
            const float dn = dinv[nd];
            half4 hv;
#pragma unroll
            for (int c = 0; c < 4; ++c) hv[c] = (half_t)(acc[c][r] * dn);
            *(half4*)(g + (size_t)nd * 64 + 4 * cl) = hv;
        }
        u0 = v0; u1 = v1; u2 = v2; u3 = v3;
        pnext = pnn;
        t = tn;
    }
    #undef ROWPTR
}

// ---------------- group-per-node gather ----------------
// 8-lane group owns one node; lane covers 8 features (16 B). Step 8: one
// csr->row round-trip covers wave-max degree (~6) for ~90% of chunks.
// Invalid steps masked by 0/1 multiplier on a safe csr[0] load.
// Buffer is bound to macro-local g_p so GATHER_G8 works with any argument name.

#define G8_STEP(K)                                                            \
        const bool v##K = sstep + K < deg;                                    \
        const int p##K = csr[v##K ? eb + sstep + K : 0];

#define G8_ROW(K)                                                             \
        const half8 r##K = *(const half8*)(g_p + (size_t)p##K * 64 + sub * 8);

#define G8_ACC(K) {                                                           \
        const float m_ = v##K ? 1.0f : 0.0f;                                  \
        acc0 = fmaf(m_, (float)r##K[0], acc0); acc1 = fmaf(m_, (float)r##K[1], acc1); \
        acc2 = fmaf(m_, (float)r##K[2], acc2); acc3 = fmaf(m_, (float)r##K[3], acc3); \
        acc4 = fmaf(m_, (float)r##K[4], acc4); acc5 = fmaf(m_, (float)r##K[5], acc5); \
        acc6 = fmaf(m_, (float)r##K[6], acc6); acc7 = fmaf(m_, (float)r##K[7], acc7); }

#define GATHER_G8(ginp)                                                       \
    const half_t* __restrict__ g_p = (ginp);                                  \
    const int n  = n0 + gi;                                                   \
    const int eb = off[n];                                                    \
    const int deg = off[n + 1] - eb;                                          \
    float acc0, acc1, acc2, acc3, acc4, acc5, acc6, acc7;                     \
    {                                                                         \
        half8 sv = *(const half8*)(g_p + (size_t)n * 64 + sub * 8);           \
        acc0 = (float)sv[0]; acc1 = (float)sv[1];                             \
        acc2 = (float)sv[2]; acc3 = (float)sv[3];                             \
        acc4 = (float)sv[4]; acc5 = (float)sv[5];                             \
        acc6 = (float)sv[6]; acc7 = (float)sv[7];                             \
    }                                                                         \
    int md = deg;                                                             \
    md = max(md, __shfl_xor(md, 8, 64));                                      \
    md = max(md, __shfl_xor(md, 16, 64));                                     \
    md = max(md, __shfl_xor(md, 32, 64));                                     \
    for (int sstep = 0; sstep < md; sstep += 8) {                             \
        G8_STEP(0) G8_STEP(1) G8_STEP(2) G8_STEP(3)                           \
        G8_STEP(4) G8_STEP(5) G8_STEP(6) G8_STEP(7)                           \
        G8_ROW(0) G8_ROW(1) G8_ROW(2) G8_ROW(3)                               \
        G8_ROW(4) G8_ROW(5) G8_ROW(6) G8_ROW(7)                               \
        G8_ACC(0) G8_ACC(1) G8_ACC(2) G8_ACC(3)                               \
        G8_ACC(4) G8_ACC(5) G8_ACC(6) G8_ACC(7)                               \
    }

// pure gather: s[n] = g[n] + sum_in g[src]   [fp16 out]
__global__ __launch_bounds__(256) void k_gather(
    const int* __restrict__ off, const int* __restrict__ csr,
    const half_t* __restrict__ gin, half_t* __restrict__ sout)
{
    const int lane = threadIdx.x & 63;
    const int gi = lane >> 3;       // group = node slot 0..7
    const int sub = lane & 7;       // feature octet
    const int wid = blockIdx.x * (blockDim.x >> 6) + (threadIdx.x >> 6);
    const int nw  = gridDim.x * (blockDim.x >> 6);

    for (int t = wid; t < NCH8; t += nw) {
        const int n0 = t * 8;
        GATHER_G8(gin)
        half8 ov;
        ov[0] = (half_t)acc0; ov[1] = (half_t)acc1;
        ov[2] = (half_t)acc2; ov[3] = (half_t)acc3;
        ov[4] = (half_t)acc4; ov[5] = (half_t)acc5;
        ov[6] = (half_t)acc6; ov[7] = (half_t)acc7;
        *(half8*)(sout + (size_t)n * 64 + sub * 8) = ov;
    }
}

// ---------------- k_mm2: g2 = (relu(dinv*s + b1) @ W2) * dinv ----------------

__global__ __launch_bounds__(256) void k_mm2(
    const float* __restrict__ W2, const float* __restrict__ b1,
    const float* __restrict__ dinv,
    const half_t* __restrict__ s, half_t* __restrict__ g)
{
    const int lane = threadIdx.x & 63;
    const int lg = lane >> 4, cl = lane & 15;
    const int wid = blockIdx.x * (blockDim.x >> 6) + (threadIdx.x >> 6);
    const int nw  = gridDim.x * (blockDim.x >> 6);

    half8 bf[2][4];
    build_bfrags(W2, lg, cl, bf);
    float bias0[8], bias1[8];
#pragma unroll
    for (int j = 0; j < 8; ++j) {
        bias0[j] = b1[8 * lg + j];
        bias1[j] = b1[32 + 8 * lg + j];
    }
    const f32x4 zacc = {0.f, 0.f, 0.f, 0.f};

    for (int t = wid; t < NGROUPS; t += nw) {
        const int n0 = t * 16;
        const int na = n0 + cl;
        const float dna = dinv[na];
        half8 s0 = *(const half8*)(s + (size_t)na * 64 + 8 * lg);
        half8 s1 = *(const half8*)(s + (size_t)na * 64 + 32 + 8 * lg);
        half8 a0, a1;
#pragma unroll
        for (int j = 0; j < 8; ++j) {
            a0[j] = (half_t)fmaxf(fmaf(dna, (float)s0[j], bias0[j]), 0.0f);
            a1[j] = (half_t)fmaxf(fmaf(dna, (float)s1[j], bias1[j]), 0.0f);
        }
        f32x4 acc[4];
#pragma unroll
        for (int c = 0; c < 4; ++c) {
            acc[c] = __builtin_amdgcn_mfma_f32_16x16x32_f16(a0, bf[0][c], zacc, 0, 0, 0);
            acc[c] = __builtin_amdgcn_mfma_f32_16x16x32_f16(a1, bf[1][c], acc[c], 0, 0, 0);
        }
#pragma unroll
        for (int r = 0; r < 4; ++r) {
            const int nd = n0 + lg * 4 + r;
            const float dn = dinv[nd];
            half4 hv;
#pragma unroll
            for (int c = 0; c < 4; ++c) hv[c] = (half_t)(acc[c][r] * dn);
            *(half4*)(g + (size_t)nd * 64 + 4 * cl) = hv;
        }
    }
}

// ---------------- gather(g2) + relu + Wp-dot fused -> pscore ----------------

__global__ __launch_bounds__(256) void k_gather_ps(
    const int* __restrict__ off, const int* __restrict__ csr,
    const float* __restrict__ b2, const float* __restrict__ Wp,
    const float* __restrict__ dinv,
    const half_t* __restrict__ g2, float* __restrict__ pscore)
{
    const int lane = threadIdx.x & 63;
    const int gi = lane >> 3;
    const int sub = lane & 7;
    const int wid = blockIdx.x * (blockDim.x >> 6) + (threadIdx.x >> 6);
    const int nw  = gridDim.x * (blockDim.x >> 6);

    float bb[8], wpu[8], wpi[8];
#pragma unroll
    for (int k = 0; k < 8; ++k) {
        bb[k]  = b2[sub * 8 + k];
        wpu[k] = Wp[sub * 8 + k];
        wpi[k] = Wp[64 + sub * 8 + k];
    }

    for (int t = wid; t < NCH8; t += nw) {
        const int n0 = t * 8;
        GATHER_G8(g2)

        const bool isu = (n0 < NUSERS);     // NUSERS%8==0: chunk uniform
        const float dn = dinv[n];
        float v = 0.0f;
#define PS_ACC(K, A) {                                                      \
        float w_ = isu ? wpu[K] : wpi[K];                                   \
        float x_ = fmaxf(fmaf(dn, (A), bb[K]), 0.0f);                       \
        v = fmaf(x_, w_, v); }
        PS_ACC(0, acc0) PS_ACC(1, acc1) PS_ACC(2, acc2) PS_ACC(3, acc3)
        PS_ACC(4, acc4) PS_ACC(5, acc5) PS_ACC(6, acc6) PS_ACC(7, acc7)
#undef PS_ACC
        v += __shfl_xor(v, 1, 64);
        v += __shfl_xor(v, 2, 64);
        v += __shfl_xor(v, 4, 64);
        if (sub == 0) pscore[n] = v;
    }
}

__global__ void k_pairs(const int* __restrict__ user_ids, const int* __restrict__ item_ids,
                        const float* __restrict__ pscore, const float* __restrict__ bp,
                        float* __restrict__ out)
{
    int b = blockIdx.x * blockDim.x + threadIdx.x;
    if (b < NUSERS)
        out[b] = pscore[user_ids[b]] + pscore[NUSERS + item_ids[b]] + bp[0];
}

// ---------------- launch ----------------
// Workspace layout (byte-exact):
//   pscore     :          0 ..   2,000,000
//   dinv       :  2,000,000 ..   4,000,000
//   offsets    :  4,000,000 ..   6,000,004   (NNODES+1 ints)
//   bbase      :  6,000,128 ..   6,001,108   (NB ints)
//   gcursor    :  6,004,224 ..   6,005,204   (NB ints)
//   csr        :  6,008,000 ..  10,808,000   (NEDGES ints)
//   bufA       : 10,808,064 ..  74,808,064   (NNODES*64 fp16)  g1, then g2
//   bufB       : 74,808,064 .. 138,808,064   s1
//   gbuf       : aliases bufB (74,808,064 .. 80,829,184) — dead before k_gather

extern "C" void kernel_launch(void* const* d_in, const int* in_sizes, int n_in,
                              void* d_out, int out_size, void* d_ws, size_t ws_size,
                              hipStream_t stream)
{
    const float* user_table = (const float*)d_in[0];
    const float* item_table = (const float*)d_in[1];
    const float* W1 = (const float*)d_in[2];
    const float* b1 = (const float*)d_in[3];
    const float* W2 = (const float*)d_in[4];
    const float* b2 = (const float*)d_in[5];
    const float* Wp = (const float*)d_in[6];
    const float* bp = (const float*)d_in[7];
    const int* edge = (const int*)d_in[8];
    const int* uid  = (const int*)d_in[9];
    const int* iid  = (const int*)d_in[10];
    float* out = (float*)d_out;

    const int* src = edge;
    const int* dst = edge + NEDGES;

    char* ws = (char*)d_ws;
    float*        pscore   = (float*)       (ws + 0);
    float*        dinv     = (float*)       (ws + 2000000);
    int*          offsets  = (int*)         (ws + 4000000);
    int*          bbase    = (int*)         (ws + 6000128);
    int*          gcursor  = (int*)         (ws + 6004224);
    int*          csr      = (int*)         (ws + 6008000);
    half_t*       bufA     = (half_t*)      (ws + 10808064);
    half_t*       bufB     = (half_t*)      (ws + 74808064);
    unsigned int* gbuf     = (unsigned int*)(ws + 74808064);   // aliases bufB

    k_zero_gc     <<<1, 256, 0, stream>>>(gcursor);
    k_bucketA     <<<NBLKA, 256, 0, stream>>>(src, dst, gcursor, gbuf);
    k_scan_buckets<<<1, 256, 0, stream>>>(gcursor, bbase);
    k_bucketB     <<<NB, 256, 0, stream>>>(gcursor, bbase, gbuf, dinv, offsets, csr);

    k_mm1      <<<2048, 256, 0, stream>>>(user_table, item_table, uid, iid, W1, dinv, bufA);
    k_gather   <<<2048, 256, 0, stream>>>(offsets, csr, bufA, bufB);
    k_mm2      <<<2048, 256, 0, stream>>>(W2, b1, dinv, bufB, bufA);
    k_gather_ps<<<2048, 256, 0, stream>>>(offsets, csr, b2, Wp, dinv, bufA, pscore);
    k_pairs    <<<(NUSERS + 255) / 256, 256, 0, stream>>>(uid, iid, pscore, bp, out);
}

// Round 16
// 195.861 us; speedup vs baseline: 1.0290x; 1.0290x over previous
//
#include <hip/hip_runtime.h>

#define NUSERS 250000
#define NITEMS 250000
#define NNODES 500000
#define NEDGES 1200000
#define NGROUPS (NNODES/16)  // 31250
#define NCH8   (NNODES/8)    // 62500

#define NB     245           // buckets: dst>>11, 2048 nodes each (last: 288)
#define BCAP   6144          // per-bucket capacity (mean 4898, +17 sigma)
#define SEGE   8192          // edges per phase-A block
#define NBLKA  147           // ceil(NEDGES/SEGE)

typedef _Float16 half_t;
typedef _Float16 half8 __attribute__((ext_vector_type(8)));
typedef _Float16 half4 __attribute__((ext_vector_type(4)));
typedef float    f32x4 __attribute__((ext_vector_type(4)));

// ---------------- CSR build: two-level LDS counting sort ----------------

__global__ void k_zero_gc(int* __restrict__ gc) {
    int t = threadIdx.x;
    if (t < NB) gc[t] = 0;
}

// Phase A: bin edges into 245 coarse buckets with LDS staging; contiguous flush.
__global__ __launch_bounds__(256) void k_bucketA(
    const int* __restrict__ src, const int* __restrict__ dst,
    int* __restrict__ gcursor, unsigned int* __restrict__ gbuf)
{
    __shared__ int ecnt[256];
    __shared__ int ebase[256];
    __shared__ int ecur[256];
    __shared__ int gres[256];
    __shared__ unsigned int stage[SEGE];
    __shared__ unsigned char stb[SEGE];

    const int t = threadIdx.x;
    const int e0 = blockIdx.x * SEGE;
    const int ecount = min(SEGE, NEDGES - e0);

    ecnt[t] = 0;
    __syncthreads();
    for (int k = t; k < ecount; k += 256)
        atomicAdd(&ecnt[dst[e0 + k] >> 11], 1);
    __syncthreads();

    const int v = ecnt[t];
    ebase[t] = v; __syncthreads();
    for (int d = 1; d < 256; d <<= 1) {
        int x = (t >= d) ? ebase[t - d] : 0;
        __syncthreads();
        ebase[t] += x;
        __syncthreads();
    }
    const int excl = ebase[t] - v;
    __syncthreads();
    ebase[t] = excl;
    ecur[t]  = excl;
    if (t < NB && v > 0) gres[t] = atomicAdd(&gcursor[t], v);
    __syncthreads();

    for (int k = t; k < ecount; k += 256) {
        const int s  = src[e0 + k];
        const int d2 = dst[e0 + k];
        const int b  = d2 >> 11;
        const int p  = atomicAdd(&ecur[b], 1);
        stage[p] = ((unsigned int)s << 11) | (unsigned int)(d2 & 2047);
        stb[p]   = (unsigned char)b;
    }
    __syncthreads();

    for (int s = t; s < ecount; s += 256) {
        const int b = stb[s];
        gbuf[(size_t)b * BCAP + gres[b] + (s - ebase[b])] = stage[s];
    }
}

// exclusive scan of the 245 bucket counts -> csr base per bucket
__global__ __launch_bounds__(256) void k_scan_buckets(const int* __restrict__ gcursor,
                                                      int* __restrict__ bbase)
{
    __shared__ int sm[256];
    const int t = threadIdx.x;
    const int v = (t < NB) ? gcursor[t] : 0;
    sm[t] = v; __syncthreads();
    for (int d = 1; d < 256; d <<= 1) {
        int x = (t >= d) ? sm[t - d] : 0;
        __syncthreads();
        sm[t] += x;
        __syncthreads();
    }
    if (t < NB) bbase[t] = sm[t] - v;
}

// Phase B: per bucket -> dinv, offsets, csr (LDS histogram/scan/place, coalesced out)
__global__ __launch_bounds__(256) void k_bucketB(
    const int* __restrict__ gcursor, const int* __restrict__ bbase,
    const unsigned int* __restrict__ gbuf,
    float* __restrict__ dinv, int* __restrict__ offsets, int* __restrict__ csr)
{
    __shared__ int hist[2048];
    __shared__ int cur[2048];
    __shared__ int psum[256];
    __shared__ int lcsr[BCAP];      // 8+8+1+24 = 41 KB LDS

    const int t = threadIdx.x;
    const int b = blockIdx.x;
    const int cnt = gcursor[b];
    const int nbase = b << 11;
    const int nb = min(2048, NNODES - nbase);
    const unsigned int* gb0 = gbuf + (size_t)b * BCAP;
    const int cbase = bbase[b];

    for (int i = t; i < 2048; i += 256) hist[i] = 0;
    __syncthreads();
    for (int s = t; s < cnt; s += 256)
        atomicAdd(&hist[gb0[s] & 2047], 1);
    __syncthreads();

    // dinv straight from histogram (self-loop adds 1)
    for (int i = t; i < nb; i += 256)
        dinv[nbase + i] = 1.0f / sqrtf((float)(hist[i] + 1));

    // exclusive scan of hist -> cur + global offsets
    int loc[8]; int ssum = 0;
#pragma unroll
    for (int k = 0; k < 8; ++k) { loc[k] = hist[t * 8 + k]; ssum += loc[k]; }
    psum[t] = ssum; __syncthreads();
    for (int d = 1; d < 256; d <<= 1) {
        int x = (t >= d) ? psum[t - d] : 0;
        __syncthreads();
        psum[t] += x;
        __syncthreads();
    }
    int run = psum[t] - ssum;
#pragma unroll
    for (int k = 0; k < 8; ++k) {
        const int i = t * 8 + k;
        if (i < nb) offsets[nbase + i] = cbase + run;
        cur[i] = run;
        run += loc[k];
    }
    __syncthreads();
    if (b == NB - 1 && t == 0) offsets[NNODES] = cbase + cnt;

    // place into LDS csr slice, then coalesced flush
    for (int s = t; s < cnt; s += 256) {
        const unsigned int pk = gb0[s];
        const int p = atomicAdd(&cur[pk & 2047], 1);
        lcsr[p] = (int)(pk >> 11);
    }
    __syncthreads();
    for (int s = t; s < cnt; s += 256)
        csr[cbase + s] = lcsr[s];
}

// ---------------- MFMA helpers ----------------
// A: lane holds row (lane&15), k = 32q + 8*(lane>>4) + j
// B: lane holds col-slot (lane&15), same k formula; out-feature = 4*(lane&15)+c
// C/D: node = n0 + (lane>>4)*4 + r, feat = 4*(lane&15)+c

__device__ __forceinline__ void build_bfrags(const float* __restrict__ W,
                                             int lg, int cl, half8 bf[2][4]) {
#pragma unroll
    for (int q = 0; q < 2; ++q)
#pragma unroll
        for (int c = 0; c < 4; ++c) {
            half8 v;
#pragma unroll
            for (int j = 0; j < 8; ++j)
                v[j] = (half_t)W[(32 * q + 8 * lg + j) * 64 + 4 * cl + c];
            bf[q][c] = v;
        }
}

// ---------------- k_mm1: g1 = (gather(emb) @ W1) * dinv  [fp16 out] ----------------
// 2-tile software pipeline (r12 form, proven): next tile's row loads issued
// before this tile's convert/MFMA/store.

__global__ __launch_bounds__(256) void k_mm1(
    const float* __restrict__ user_table, const float* __restrict__ item_table,
    const int* __restrict__ uid, const int* __restrict__ iid,
    const float* __restrict__ W1, const float* __restrict__ dinv,
    half_t* __restrict__ g)
{
    const int lane = threadIdx.x & 63;
    const int lg = lane >> 4, cl = lane & 15;
    const int wid = blockIdx.x * (blockDim.x >> 6) + (threadIdx.x >> 6);
    const int nw  = gridDim.x * (blockDim.x >> 6);

    half8 bf[2][4];
    build_bfrags(W1, lg, cl, bf);
    const f32x4 zacc = {0.f, 0.f, 0.f, 0.f};

    int t = wid;
    f32x4 u0, u1, u2, u3;
    if (t < NGROUPS) {
        const int na = t * 16 + cl;                // NUSERS%16==0: tiles never straddle
        const float* p = (na < NUSERS)
            ? user_table + (size_t)uid[na] * 64
            : item_table + (size_t)iid[na - NUSERS] * 64;
        u0 = *(const f32x4*)(p + 8 * lg);
        u1 = *(const f32x4*)(p + 8 * lg + 4);
        u2 = *(const f32x4*)(p + 8 * lg + 32);
        u3 = *(const f32x4*)(p + 8 * lg + 36);
    }
    while (t < NGROUPS) {
        const int tn = t + nw;
        const int tl = (tn < NGROUPS) ? tn : t;    // safe reload on last iter
        const int nb2 = tl * 16 + cl;
        const float* pn = (nb2 < NUSERS)
            ? user_table + (size_t)uid[nb2] * 64
            : item_table + (size_t)iid[nb2 - NUSERS] * 64;
        f32x4 v0 = *(const f32x4*)(pn + 8 * lg);
        f32x4 v1 = *(const f32x4*)(pn + 8 * lg + 4);
        f32x4 v2 = *(const f32x4*)(pn + 8 * lg + 32);
        f32x4 v3 = *(const f32x4*)(pn + 8 * lg + 36);

        const int n0 = t * 16;
        half8 a0, a1;
#pragma unroll
        for (int j = 0; j < 4; ++j) {
            a0[j] = (half_t)u0[j]; a0[4 + j] = (half_t)u1[j];
            a1[j] = (half_t)u2[j]; a1[4 + j] = (half_t)u3[j];
        }
        f32x4 acc[4];
#pragma unroll
        for (int c = 0; c < 4; ++c) {
            acc[c] = __builtin_amdgcn_mfma_f32_16x16x32_f16(a0, bf[0][c], zacc, 0, 0, 0);
            acc[c] = __builtin_amdgcn_mfma_f32_16x16x32_f16(a1, bf[1][c], acc[c], 0, 0, 0);
        }
#pragma unroll
        for (int r = 0; r < 4; ++r) {
            const int nd = n0 + lg * 4 + r;
            const float dn = dinv[nd];
            half4 hv;
#pragma unroll
            for (int c = 0; c < 4; ++c) hv[c] = (half_t)(acc[c][r] * dn);
            *(half4*)(g + (size_t)nd * 64 + 4 * cl) = hv;
        }
        u0 = v0; u1 = v1; u2 = v2; u3 = v3;
        t = tn;
    }
}

// ---------------- k_gather_mm2: fused gather(g1) + layer2 MFMA -> g2 ----------------
// The gather runs DIRECTLY in A-fragment layout: lane (cl,lg) owns node n0+cl,
// feature slices [8lg,8lg+8) and [32+8lg,+8). Accumulates in 16 f32 regs over
// the node's edge list (4 edges unrolled -> 8 row-load instructions cover 64
// edges in flight across the wave). No LDS, no intermediate s1 buffer.

__global__ __launch_bounds__(256) void k_gather_mm2(
    const int* __restrict__ off, const int* __restrict__ csr,
    const float* __restrict__ W2, const float* __restrict__ b1,
    const float* __restrict__ dinv,
    const half_t* __restrict__ g1, half_t* __restrict__ g2)
{
    const int lane = threadIdx.x & 63;
    const int lg = lane >> 4, cl = lane & 15;
    const int wid = blockIdx.x * (blockDim.x >> 6) + (threadIdx.x >> 6);
    const int nw  = gridDim.x * (blockDim.x >> 6);

    half8 bf[2][4];
    build_bfrags(W2, lg, cl, bf);
    float bias0[8], bias1[8];
#pragma unroll
    for (int j = 0; j < 8; ++j) {
        bias0[j] = b1[8 * lg + j];
        bias1[j] = b1[32 + 8 * lg + j];
    }
    const f32x4 zacc = {0.f, 0.f, 0.f, 0.f};

    for (int t = wid; t < NGROUPS; t += nw) {
        const int n0 = t * 16;
        const int n  = n0 + cl;
        const int eb = off[n];
        const int deg = off[n + 1] - eb;

        float f0[8], f1[8];
        {
            half8 s0 = *(const half8*)(g1 + (size_t)n * 64 + 8 * lg);
            half8 s1 = *(const half8*)(g1 + (size_t)n * 64 + 32 + 8 * lg);
#pragma unroll
            for (int j = 0; j < 8; ++j) { f0[j] = (float)s0[j]; f1[j] = (float)s1[j]; }
        }

        // wave-max degree (deg depends only on cl; reduce within 16-lane groups)
        int md = deg;
        md = max(md, __shfl_xor(md, 1, 64));
        md = max(md, __shfl_xor(md, 2, 64));
        md = max(md, __shfl_xor(md, 4, 64));
        md = max(md, __shfl_xor(md, 8, 64));

        for (int ss = 0; ss < md; ss += 4) {
            const bool v0 = ss < deg,     v1 = ss + 1 < deg;
            const bool v2 = ss + 2 < deg, v3 = ss + 3 < deg;
            const int p0 = csr[v0 ? eb + ss     : 0];
            const int p1 = csr[v1 ? eb + ss + 1 : 0];
            const int p2 = csr[v2 ? eb + ss + 2 : 0];
            const int p3 = csr[v3 ? eb + ss + 3 : 0];
            const half8 r00 = *(const half8*)(g1 + (size_t)p0 * 64 + 8 * lg);
            const half8 r01 = *(const half8*)(g1 + (size_t)p0 * 64 + 32 + 8 * lg);
            const half8 r10 = *(const half8*)(g1 + (size_t)p1 * 64 + 8 * lg);
            const half8 r11 = *(const half8*)(g1 + (size_t)p1 * 64 + 32 + 8 * lg);
            const half8 r20 = *(const half8*)(g1 + (size_t)p2 * 64 + 8 * lg);
            const half8 r21 = *(const half8*)(g1 + (size_t)p2 * 64 + 32 + 8 * lg);
            const half8 r30 = *(const half8*)(g1 + (size_t)p3 * 64 + 8 * lg);
            const half8 r31 = *(const half8*)(g1 + (size_t)p3 * 64 + 32 + 8 * lg);
            const float m0 = v0 ? 1.0f : 0.0f;
            const float m1 = v1 ? 1.0f : 0.0f;
            const float m2 = v2 ? 1.0f : 0.0f;
            const float m3 = v3 ? 1.0f : 0.0f;
#pragma unroll
            for (int j = 0; j < 8; ++j) {
                f0[j] = fmaf(m0, (float)r00[j], f0[j]);
                f1[j] = fmaf(m0, (float)r01[j], f1[j]);
            }
#pragma unroll
            for (int j = 0; j < 8; ++j) {
                f0[j] = fmaf(m1, (float)r10[j], f0[j]);
                f1[j] = fmaf(m1, (float)r11[j], f1[j]);
            }
#pragma unroll
            for (int j = 0; j < 8; ++j) {
                f0[j] = fmaf(m2, (float)r20[j], f0[j]);
                f1[j] = fmaf(m2, (float)r21[j], f1[j]);
            }
#pragma unroll
            for (int j = 0; j < 8; ++j) {
                f0[j] = fmaf(m3, (float)r30[j], f0[j]);
                f1[j] = fmaf(m3, (float)r31[j], f1[j]);
            }
        }

        // x1 = relu(dinv*sum + b1) in A-fragment layout, then @W2, *dinv
        const float dna = dinv[n];
        half8 a0, a1;
#pragma unroll
        for (int j = 0; j < 8; ++j) {
            a0[j] = (half_t)fmaxf(fmaf(dna, f0[j], bias0[j]), 0.0f);
            a1[j] = (half_t)fmaxf(fmaf(dna, f1[j], bias1[j]), 0.0f);
        }
        f32x4 acc[4];
#pragma unroll
        for (int c = 0; c < 4; ++c) {
            acc[c] = __builtin_amdgcn_mfma_f32_16x16x32_f16(a0, bf[0][c], zacc, 0, 0, 0);
            acc[c] = __builtin_amdgcn_mfma_f32_16x16x32_f16(a1, bf[1][c], acc[c], 0, 0, 0);
        }
#pragma unroll
        for (int r = 0; r < 4; ++r) {
            const int nd = n0 + lg * 4 + r;
            const float dn = dinv[nd];
            half4 hv;
#pragma unroll
            for (int c = 0; c < 4; ++c) hv[c] = (half_t)(acc[c][r] * dn);
            *(half4*)(g2 + (size_t)nd * 64 + 4 * cl) = hv;
        }
    }
}

// ---------------- group-per-node gather + relu + Wp-dot fused -> pscore ----------------
// 8-lane group owns one node; lane covers 8 features (16 B). Step 8: one
// csr->row round-trip covers wave-max degree for ~90% of chunks.

#define G8_STEP(K)                                                            \
        const bool v##K = sstep + K < deg;                                    \
        const int p##K = csr[v##K ? eb + sstep + K : 0];

#define G8_ROW(K)                                                             \
        const half8 r##K = *(const half8*)(g_p + (size_t)p##K * 64 + sub * 8);

#define G8_ACC(K) {                                                           \
        const float m_ = v##K ? 1.0f : 0.0f;                                  \
        acc0 = fmaf(m_, (float)r##K[0], acc0); acc1 = fmaf(m_, (float)r##K[1], acc1); \
        acc2 = fmaf(m_, (float)r##K[2], acc2); acc3 = fmaf(m_, (float)r##K[3], acc3); \
        acc4 = fmaf(m_, (float)r##K[4], acc4); acc5 = fmaf(m_, (float)r##K[5], acc5); \
        acc6 = fmaf(m_, (float)r##K[6], acc6); acc7 = fmaf(m_, (float)r##K[7], acc7); }

#define GATHER_G8(ginp)                                                       \
    const half_t* __restrict__ g_p = (ginp);                                  \
    const int n  = n0 + gi;                                                   \
    const int eb = off[n];                                                    \
    const int deg = off[n + 1] - eb;                                          \
    float acc0, acc1, acc2, acc3, acc4, acc5, acc6, acc7;                     \
    {                                                                         \
        half8 sv = *(const half8*)(g_p + (size_t)n * 64 + sub * 8);           \
        acc0 = (float)sv[0]; acc1 = (float)sv[1];                             \
        acc2 = (float)sv[2]; acc3 = (float)sv[3];                             \
        acc4 = (float)sv[4]; acc5 = (float)sv[5];                             \
        acc6 = (float)sv[6]; acc7 = (float)sv[7];                             \
    }                                                                         \
    int md = deg;                                                             \
    md = max(md, __shfl_xor(md, 8, 64));                                      \
    md = max(md, __shfl_xor(md, 16, 64));                                     \
    md = max(md, __shfl_xor(md, 32, 64));                                     \
    for (int sstep = 0; sstep < md; sstep += 8) {                             \
        G8_STEP(0) G8_STEP(1) G8_STEP(2) G8_STEP(3)                           \
        G8_STEP(4) G8_STEP(5) G8_STEP(6) G8_STEP(7)                           \
        G8_ROW(0) G8_ROW(1) G8_ROW(2) G8_ROW(3)                               \
        G8_ROW(4) G8_ROW(5) G8_ROW(6) G8_ROW(7)                               \
        G8_ACC(0) G8_ACC(1) G8_ACC(2) G8_ACC(3)                               \
        G8_ACC(4) G8_ACC(5) G8_ACC(6) G8_ACC(7)                               \
    }

__global__ __launch_bounds__(256) void k_gather_ps(
    const int* __restrict__ off, const int* __restrict__ csr,
    const float* __restrict__ b2, const float* __restrict__ Wp,
    const float* __restrict__ dinv,
    const half_t* __restrict__ g2, float* __restrict__ pscore)
{
    const int lane = threadIdx.x & 63;
    const int gi = lane >> 3;
    const int sub = lane & 7;
    const int wid = blockIdx.x * (blockDim.x >> 6) + (threadIdx.x >> 6);
    const int nw  = gridDim.x * (blockDim.x >> 6);

    float bb[8], wpu[8], wpi[8];
#pragma unroll
    for (int k = 0; k < 8; ++k) {
        bb[k]  = b2[sub * 8 + k];
        wpu[k] = Wp[sub * 8 + k];
        wpi[k] = Wp[64 + sub * 8 + k];
    }

    for (int t = wid; t < NCH8; t += nw) {
        const int n0 = t * 8;
        GATHER_G8(g2)

        const bool isu = (n0 < NUSERS);     // NUSERS%8==0: chunk uniform
        const float dn = dinv[n];
        float v = 0.0f;
#define PS_ACC(K, A) {                                                      \
        float w_ = isu ? wpu[K] : wpi[K];                                   \
        float x_ = fmaxf(fmaf(dn, (A), bb[K]), 0.0f);                       \
        v = fmaf(x_, w_, v); }
        PS_ACC(0, acc0) PS_ACC(1, acc1) PS_ACC(2, acc2) PS_ACC(3, acc3)
        PS_ACC(4, acc4) PS_ACC(5, acc5) PS_ACC(6, acc6) PS_ACC(7, acc7)
#undef PS_ACC
        v += __shfl_xor(v, 1, 64);
        v += __shfl_xor(v, 2, 64);
        v += __shfl_xor(v, 4, 64);
        if (sub == 0) pscore[n] = v;
    }
}

__global__ void k_pairs(const int* __restrict__ user_ids, const int* __restrict__ item_ids,
                        const float* __restrict__ pscore, const float* __restrict__ bp,
                        float* __restrict__ out)
{
    int b = blockIdx.x * blockDim.x + threadIdx.x;
    if (b < NUSERS)
        out[b] = pscore[user_ids[b]] + pscore[NUSERS + item_ids[b]] + bp[0];
}

// ---------------- launch ----------------
// Workspace layout (byte-exact):
//   pscore     :          0 ..   2,000,000
//   dinv       :  2,000,000 ..   4,000,000
//   offsets    :  4,000,000 ..   6,000,004   (NNODES+1 ints)
//   bbase      :  6,000,128 ..   6,001,108   (NB ints)
//   gcursor    :  6,004,224 ..   6,005,204   (NB ints)
//   csr        :  6,008,000 ..  10,808,000   (NEDGES ints)
//   bufA (g1)  : 10,808,064 ..  74,808,064   (NNODES*64 fp16)
//   bufB (g2)  : 74,808,064 .. 138,808,064
//   gbuf       : aliases bufB (74,808,064 .. 80,829,184) — dead before k_gather_mm2

extern "C" void kernel_launch(void* const* d_in, const int* in_sizes, int n_in,
                              void* d_out, int out_size, void* d_ws, size_t ws_size,
                              hipStream_t stream)
{
    const float* user_table = (const float*)d_in[0];
    const float* item_table = (const float*)d_in[1];
    const float* W1 = (const float*)d_in[2];
    const float* b1 = (const float*)d_in[3];
    const float* W2 = (const float*)d_in[4];
    const float* b2 = (const float*)d_in[5];
    const float* Wp = (const float*)d_in[6];
    const float* bp = (const float*)d_in[7];
    const int* edge = (const int*)d_in[8];
    const int* uid  = (const int*)d_in[9];
    const int* iid  = (const int*)d_in[10];
    float* out = (float*)d_out;

    const int* src = edge;
    const int* dst = edge + NEDGES;

    char* ws = (char*)d_ws;
    float*        pscore   = (float*)       (ws + 0);
    float*        dinv     = (float*)       (ws + 2000000);
    int*          offsets  = (int*)         (ws + 4000000);
    int*          bbase    = (int*)         (ws + 6000128);
    int*          gcursor  = (int*)         (ws + 6004224);
    int*          csr      = (int*)         (ws + 6008000);
    half_t*       bufA     = (half_t*)      (ws + 10808064);
    half_t*       bufB     = (half_t*)      (ws + 74808064);
    unsigned int* gbuf     = (unsigned int*)(ws + 74808064);   // aliases bufB

    k_zero_gc     <<<1, 256, 0, stream>>>(gcursor);
    k_bucketA     <<<NBLKA, 256, 0, stream>>>(src, dst, gcursor, gbuf);
    k_scan_buckets<<<1, 256, 0, stream>>>(gcursor, bbase);
    k_bucketB     <<<NB, 256, 0, stream>>>(gcursor, bbase, gbuf, dinv, offsets, csr);

    k_mm1       <<<2048, 256, 0, stream>>>(user_table, item_table, uid, iid, W1, dinv, bufA);
    k_gather_mm2<<<2048, 256, 0, stream>>>(offsets, csr, W2, b1, dinv, bufA, bufB);
    k_gather_ps <<<2048, 256, 0, stream>>>(offsets, csr, b2, Wp, dinv, bufB, pscore);
    k_pairs     <<<(NUSERS + 255) / 256, 256, 0, stream>>>(uid, iid, pscore, bp, out);
}